// Round 12
// baseline (216.647 us; speedup 1.0000x reference)
//
#include <hip/hip_runtime.h>

// GestureRNN v19b: v19 with the cvt_pkrtz type fix (__fp16 vec -> bit_cast).
// B=4096, T=512, IN=10, H=32, NCLS=9.
//
// v19 failed to COMPILE (cvt_pkrtz returns __fp16x2, not _Float16x2); no perf
// data. Theory carried over from R10: depth-4 xp register pipeline (step r
// consumes xp(r), regenerates xp(r+4) -> ~400-500 cyc of issue slack hides
// the frag ds_read + 3-deep MFMA accumulate chain completely), pkrtz packing
// halves cvt VALU on the MFMA->VALU->MFMA recurrence chain.
// Layout conjugation K(k)=16*((k>>2)&1)+4*(k>>3)+(k&3) HW-verified (v12+).
// 256 blocks x 1 wave.

constexpr int T_  = 512;
constexpr int IN_ = 10;
constexpr int H_  = 32;
constexpr int NC_ = 9;
constexpr int CT_ = 16;        // timesteps per chunk
constexpr int NCH = T_ / CT_;  // 32 chunks

typedef _Float16 f16x8 __attribute__((ext_vector_type(8)));
typedef _Float16 h2t  __attribute__((ext_vector_type(2)));
typedef float    f32x4 __attribute__((ext_vector_type(4)));

union H8 { f16x8 v; h2t h[4]; unsigned int u[4]; };

__device__ __forceinline__ void cfence() { __asm__ volatile("" ::: "memory"); }

__device__ __forceinline__ f32x4 MFMA(f16x8 a, f16x8 b, f32x4 c) {
    return __builtin_amdgcn_mfma_f32_16x16x32_f16(a, b, c, 0, 0, 0);
}

// packed f32x2 -> f16x2 (RTZ), bit_cast to our _Float16 vec type
__device__ __forceinline__ h2t PK(float a, float b) {
    return __builtin_bit_cast(h2t, __builtin_amdgcn_cvt_pkrtz(a, b));
}

__global__ __launch_bounds__(64, 1)
__attribute__((amdgpu_waves_per_eu(1, 1)))
void gesture_rnn_kernel(
    const float* __restrict__ x,      // [B, T, IN]
    const float* __restrict__ W_ih0,  // [H, IN]
    const float* __restrict__ W_hh0,  // [H, H]
    const float* __restrict__ b_ih0,  // [H]
    const float* __restrict__ b_hh0,  // [H]
    const float* __restrict__ W_ih1,  // [H, H]
    const float* __restrict__ W_hh1,  // [H, H]
    const float* __restrict__ b_ih1,  // [H]
    const float* __restrict__ b_hh1,  // [H]
    const float* __restrict__ W_fc,   // [NC, H]
    const float* __restrict__ b_fc,   // [NC]
    float* __restrict__ out)          // [B, NC]
{
    const int lane = threadIdx.x;     // 0..63
    const int c    = lane & 15;       // batch col (B/C col, A row)
    const int g    = lane >> 4;       // k-group: holds k = 8g..8g+7
    const long b   = (long)blockIdx.x * 16 + c;

    // ---- A-fragments (k-order K(k) for recurrent mats; natural for xproj) --
    f16x8 ah0[2], ai1[2], ah1[2], axh[2], axl[2];
#pragma unroll
    for (int Tt = 0; Tt < 2; ++Tt) {
#pragma unroll
        for (int j = 0; j < 8; ++j) {
            const int k   = 8 * g + j;
            const int kp  = 16 * ((k >> 2) & 1) + 4 * (k >> 3) + (k & 3);
            const int row = 16 * Tt + c;
            ah0[Tt][j] = (_Float16)W_hh0[row * H_ + kp];
            ai1[Tt][j] = (_Float16)W_ih1[row * H_ + kp];
            ah1[Tt][j] = (_Float16)W_hh1[row * H_ + kp];
            const float wx = (k < IN_) ? W_ih0[row * IN_ + k] : 0.f;
            const _Float16 wh = (_Float16)wx;
            axh[Tt][j] = wh;
            axl[Tt][j] = (_Float16)(wx - (float)wh);
        }
    }
    f32x4 b0i[2], b1i[2];
#pragma unroll
    for (int Tt = 0; Tt < 2; ++Tt)
#pragma unroll
        for (int r = 0; r < 4; ++r) {
            const int uu = 16 * Tt + 4 * g + r;
            b0i[Tt][r] = b_ih0[uu] + b_hh0[uu];
            b1i[Tt][r] = b_ih1[uu] + b_hh1[uu];
        }

    // ---- LDS: packed-f16 x B-fragments, double-buffered ----
    __shared__ uint4 xhl[2][2][CT_][2][16];  // [buf][hi/lo][t][g01][c]
    __shared__ uint4 zs4;                    // zero frag for g>=2 lanes
    __shared__ _Float16 hfin[16][H_];

    if (lane == 0) zs4 = make_uint4(0u, 0u, 0u, 0u);

    // ---- x load: lane(g,c) owns timesteps 4g+s (s=0..3) of batch b ----
    float xr[4][IN_];
    const float* xg = x + ((size_t)b * T_ + 4 * g) * IN_;
#pragma unroll
    for (int s = 0; s < 4; ++s)
#pragma unroll
        for (int i = 0; i < IN_; i += 2) {
            const float2 v = *(const float2*)(xg + s * IN_ + i);
            xr[s][i] = v.x; xr[s][i + 1] = v.y;
        }
    xg += CT_ * IN_;

    // per-lane read pointers: g<2 reads its fragment slice, g>=2 the zero slot
    const int tmul = (g < 2) ? 32 : 0;       // uint4 stride per t
    const uint4* hpA = (g < 2) ? &xhl[0][0][0][g][c] : &zs4;
    const uint4* lpA = (g < 2) ? &xhl[0][1][0][g][c] : &zs4;
    const uint4* hpB = (g < 2) ? &xhl[1][0][0][g][c] : &zs4;
    const uint4* lpB = (g < 2) ? &xhl[1][1][0][g][c] : &zs4;

    f16x8 h1f, h2f;
#pragma unroll
    for (int j = 0; j < 8; ++j) { h1f[j] = (_Float16)0.f; h2f[j] = (_Float16)0.f; }

    // depth-4 xp pipeline: set q holds xp(t) with t = q (mod 4)
    f32x4 xq0a, xq0b, xq1a, xq1b, xq2a, xq2b, xq3a, xq3b;

    // ---- DUMP(BUF, PREFETCH): convert xr -> packed f16 hi/lo frags in LDS --
#define DUMP(BUF, PREFETCH)                                                  \
    {                                                                        \
        _Pragma("unroll")                                                    \
        for (int s_ = 0; s_ < 4; ++s_) {                                     \
            const int t_ = 4 * g + s_;                                       \
            unsigned int hd_[5], ld_[5];                                     \
            _Pragma("unroll")                                                \
            for (int p_ = 0; p_ < 5; ++p_) {                                 \
                const float a_ = xr[s_][2 * p_], q_ = xr[s_][2 * p_ + 1];    \
                const _Float16 ha_ = (_Float16)a_, hb_ = (_Float16)q_;       \
                h2t hh_; hh_[0] = ha_; hh_[1] = hb_;                         \
                hd_[p_] = __builtin_bit_cast(unsigned int, hh_);             \
                h2t ll_; ll_[0] = (_Float16)(a_ - (float)ha_);               \
                ll_[1] = (_Float16)(q_ - (float)hb_);                        \
                ld_[p_] = __builtin_bit_cast(unsigned int, ll_);             \
            }                                                                \
            xhl[BUF][0][t_][0][c] = make_uint4(hd_[0], hd_[1], hd_[2], hd_[3]); \
            xhl[BUF][0][t_][1][c] = make_uint4(hd_[4], 0u, 0u, 0u);          \
            xhl[BUF][1][t_][0][c] = make_uint4(ld_[0], ld_[1], ld_[2], ld_[3]); \
            xhl[BUF][1][t_][1][c] = make_uint4(ld_[4], 0u, 0u, 0u);          \
        }                                                                    \
        if (PREFETCH) {                                                      \
            _Pragma("unroll")                                                \
            for (int s_ = 0; s_ < 4; ++s_)                                   \
                _Pragma("unroll")                                            \
                for (int i_ = 0; i_ < IN_; i_ += 2) {                        \
                    const float2 v_ = *(const float2*)(xg + s_ * IN_ + i_);  \
                    xr[s_][i_] = v_.x; xr[s_][i_ + 1] = v_.y;                \
                }                                                            \
            xg += CT_ * IN_;                                                 \
        }                                                                    \
        cfence();                                                            \
    }

    // ---- XFQ: xp(TT) = W_ih0 @ x[TT] + b0 (frag ds_read + 3-term split).
    //      Result consumed FOUR steps later -> chain fully hidden. ----
#define XFQ(TT, P0, P1, HP, LP)                                              \
    {                                                                        \
        const uint4 bhu_ = (HP)[(TT) * tmul];                                \
        const uint4 blu_ = (LP)[(TT) * tmul];                                \
        const f16x8 BH_ = __builtin_bit_cast(f16x8, bhu_);                   \
        const f16x8 BL_ = __builtin_bit_cast(f16x8, blu_);                   \
        P0 = MFMA(axh[0], BH_, b0i[0]);                                      \
        P1 = MFMA(axh[1], BH_, b0i[1]);                                      \
        P0 = MFMA(axh[0], BL_, P0);                                          \
        P1 = MFMA(axh[1], BL_, P1);                                          \
        P0 = MFMA(axl[0], BH_, P0);                                          \
        P1 = MFMA(axl[1], BH_, P1);                                          \
    }

    // ---- STEPQ: consume xp set Q (= xp(r)); optionally regen Q = xp(r+4).
    //      h-state packed via cvt_pkrtz (2 f32 -> f16x2). ----
#define STEPQ(Q0, Q1, DOX, TT, HP, LP)                                       \
    {                                                                        \
        const f32x4 c0_ = MFMA(ah0[0], h1f, Q0);                             \
        const f32x4 c1_ = MFMA(ah0[1], h1f, Q1);                             \
        f32x4 d0_ = MFMA(ai1[0], h1f, b1i[0]);                               \
        f32x4 d1_ = MFMA(ai1[1], h1f, b1i[1]);                               \
        d0_ = MFMA(ah1[0], h2f, d0_);                                        \
        d1_ = MFMA(ah1[1], h2f, d1_);                                        \
        if (DOX) { XFQ(TT, Q0, Q1, HP, LP) }                                 \
        H8 n1_, n2_;                                                         \
        n1_.h[0] = PK(fmaxf(c0_[0], 0.f), fmaxf(c0_[1], 0.f));               \
        n1_.h[1] = PK(fmaxf(c0_[2], 0.f), fmaxf(c0_[3], 0.f));               \
        n1_.h[2] = PK(fmaxf(c1_[0], 0.f), fmaxf(c1_[1], 0.f));               \
        n1_.h[3] = PK(fmaxf(c1_[2], 0.f), fmaxf(c1_[3], 0.f));               \
        n2_.h[0] = PK(fmaxf(d0_[0], 0.f), fmaxf(d0_[1], 0.f));               \
        n2_.h[1] = PK(fmaxf(d0_[2], 0.f), fmaxf(d0_[3], 0.f));               \
        n2_.h[2] = PK(fmaxf(d1_[0], 0.f), fmaxf(d1_[1], 0.f));               \
        n2_.h[3] = PK(fmaxf(d1_[2], 0.f), fmaxf(d1_[3], 0.f));               \
        h1f = n1_.v; h2f = n2_.v;                                            \
    }

    // ---- chunk 0 prologue: stage, prime xp(0..3), special step 0 ----
    DUMP(0, 1);                          // stage chunk 0, prefetch chunk 1
    XFQ(0, xq0a, xq0b, hpA, lpA);
    XFQ(1, xq1a, xq1b, hpA, lpA);
    XFQ(2, xq2a, xq2b, hpA, lpA);
    XFQ(3, xq3a, xq3b, hpA, lpA);
    {
        // special step 0: h1[0] = relu(xp(0)); h2[-1] = 0
        H8 n1;
        n1.h[0] = PK(fmaxf(xq0a[0], 0.f), fmaxf(xq0a[1], 0.f));
        n1.h[1] = PK(fmaxf(xq0a[2], 0.f), fmaxf(xq0a[3], 0.f));
        n1.h[2] = PK(fmaxf(xq0b[0], 0.f), fmaxf(xq0b[1], 0.f));
        n1.h[3] = PK(fmaxf(xq0b[2], 0.f), fmaxf(xq0b[3], 0.f));
        h1f = n1.v;                      // h2f stays 0
        XFQ(4, xq0a, xq0b, hpA, lpA);    // regen set 0 = xp(4)
    }
    STEPQ(xq1a, xq1b, 1, 5,  hpA, lpA);  // r=1
    STEPQ(xq2a, xq2b, 1, 6,  hpA, lpA);  // r=2
    STEPQ(xq3a, xq3b, 1, 7,  hpA, lpA);  // r=3
    STEPQ(xq0a, xq0b, 1, 8,  hpA, lpA);  // r=4
    STEPQ(xq1a, xq1b, 1, 9,  hpA, lpA);  // r=5
    STEPQ(xq2a, xq2b, 1, 10, hpA, lpA);  // r=6
    STEPQ(xq3a, xq3b, 1, 11, hpA, lpA);  // r=7
    DUMP(1, 1);                          // stage chunk 1, prefetch chunk 2
    STEPQ(xq0a, xq0b, 1, 12, hpA, lpA);  // r=8
    STEPQ(xq1a, xq1b, 1, 13, hpA, lpA);  // r=9
    STEPQ(xq2a, xq2b, 1, 14, hpA, lpA);  // r=10
    STEPQ(xq3a, xq3b, 1, 15, hpA, lpA);  // r=11
    STEPQ(xq0a, xq0b, 1, 0,  hpB, lpB);  // r=12 -> xp(0) of chunk 1
    STEPQ(xq1a, xq1b, 1, 1,  hpB, lpB);  // r=13
    STEPQ(xq2a, xq2b, 1, 2,  hpB, lpB);  // r=14
    STEPQ(xq3a, xq3b, 1, 3,  hpB, lpB);  // r=15

    // ---- chunks 1..30 ----
    const uint4 *hpc = hpB, *lpc = lpB, *hpn = hpA, *lpn = lpA;
    int wbuf = 0;                        // buffer DUMPed this iteration (=nxt)
#pragma unroll 1
    for (int n = 1; n <= 30; ++n) {
        STEPQ(xq0a, xq0b, 1, 4,  hpc, lpc);   // r=0
        STEPQ(xq1a, xq1b, 1, 5,  hpc, lpc);
        STEPQ(xq2a, xq2b, 1, 6,  hpc, lpc);
        STEPQ(xq3a, xq3b, 1, 7,  hpc, lpc);
        STEPQ(xq0a, xq0b, 1, 8,  hpc, lpc);   // r=4
        STEPQ(xq1a, xq1b, 1, 9,  hpc, lpc);
        STEPQ(xq2a, xq2b, 1, 10, hpc, lpc);
        STEPQ(xq3a, xq3b, 1, 11, hpc, lpc);   // r=7
        DUMP(wbuf, (n < 30));                 // stage chunk n+1, prefetch n+2
        STEPQ(xq0a, xq0b, 1, 12, hpc, lpc);   // r=8
        STEPQ(xq1a, xq1b, 1, 13, hpc, lpc);
        STEPQ(xq2a, xq2b, 1, 14, hpc, lpc);
        STEPQ(xq3a, xq3b, 1, 15, hpc, lpc);   // r=11
        STEPQ(xq0a, xq0b, 1, 0,  hpn, lpn);   // r=12 -> xp(0) next chunk
        STEPQ(xq1a, xq1b, 1, 1,  hpn, lpn);
        STEPQ(xq2a, xq2b, 1, 2,  hpn, lpn);
        STEPQ(xq3a, xq3b, 1, 3,  hpn, lpn);   // r=15
        const uint4* t1 = hpc; hpc = hpn; hpn = t1;
        const uint4* t2 = lpc; lpc = lpn; lpn = t2;
        wbuf ^= 1;
    }

    // ---- chunk 31 (no staging; r>=12 no regen) ----
    STEPQ(xq0a, xq0b, 1, 4,  hpc, lpc);
    STEPQ(xq1a, xq1b, 1, 5,  hpc, lpc);
    STEPQ(xq2a, xq2b, 1, 6,  hpc, lpc);
    STEPQ(xq3a, xq3b, 1, 7,  hpc, lpc);
    STEPQ(xq0a, xq0b, 1, 8,  hpc, lpc);
    STEPQ(xq1a, xq1b, 1, 9,  hpc, lpc);
    STEPQ(xq2a, xq2b, 1, 10, hpc, lpc);
    STEPQ(xq3a, xq3b, 1, 11, hpc, lpc);
    STEPQ(xq0a, xq0b, 1, 12, hpc, lpc);
    STEPQ(xq1a, xq1b, 1, 13, hpc, lpc);
    STEPQ(xq2a, xq2b, 1, 14, hpc, lpc);
    STEPQ(xq3a, xq3b, 1, 15, hpc, lpc);
    STEPQ(xq0a, xq0b, 0, 0, hpc, lpc);   // r=12
    STEPQ(xq1a, xq1b, 0, 0, hpc, lpc);   // r=13
    STEPQ(xq2a, xq2b, 0, 0, hpc, lpc);   // r=14
    STEPQ(xq3a, xq3b, 0, 0, hpc, lpc);   // r=15

    // ---- epilogue: h2[511] = relu(b1 + W_ih1.h1[511] + W_hh1.h2[510]) ----
    {
        f32x4 d0 = MFMA(ai1[0], h1f, b1i[0]);
        f32x4 d1 = MFMA(ai1[1], h1f, b1i[1]);
        d0 = MFMA(ah1[0], h2f, d0);
        d1 = MFMA(ah1[1], h2f, d1);
        H8 n2;
        n2.h[0] = PK(fmaxf(d0[0], 0.f), fmaxf(d0[1], 0.f));
        n2.h[1] = PK(fmaxf(d0[2], 0.f), fmaxf(d0[3], 0.f));
        n2.h[2] = PK(fmaxf(d1[0], 0.f), fmaxf(d1[1], 0.f));
        n2.h[3] = PK(fmaxf(d1[2], 0.f), fmaxf(d1[3], 0.f));
        h2f = n2.v;
    }

    // ---- FC head ----
#pragma unroll
    for (int r = 0; r < 4; ++r) {
        hfin[c][4 * g + r]      = h2f[r];
        hfin[c][16 + 4 * g + r] = h2f[4 + r];
    }
    cfence();   // single-wave in-order DS pipe
    {
        float acc0 = b_fc[g];
        float acc1 = b_fc[g + 4];
        float acc2 = (g == 0) ? b_fc[8] : 0.f;
#pragma unroll
        for (int k = 0; k < H_; ++k) {
            const float hv = (float)hfin[c][k];
            acc0 = fmaf(W_fc[g * H_ + k], hv, acc0);
            acc1 = fmaf(W_fc[(g + 4) * H_ + k], hv, acc1);
            if (g == 0) acc2 = fmaf(W_fc[8 * H_ + k], hv, acc2);
        }
        out[b * NC_ + g]     = acc0;
        out[b * NC_ + g + 4] = acc1;
        if (g == 0) out[b * NC_ + 8] = acc2;
    }
#undef DUMP
#undef XFQ
#undef STEPQ
}

extern "C" void kernel_launch(void* const* d_in, const int* in_sizes, int n_in,
                              void* d_out, int out_size, void* d_ws, size_t ws_size,
                              hipStream_t stream) {
    const float* x     = (const float*)d_in[0];
    const float* W_ih0 = (const float*)d_in[1];
    const float* W_hh0 = (const float*)d_in[2];
    const float* b_ih0 = (const float*)d_in[3];
    const float* b_hh0 = (const float*)d_in[4];
    const float* W_ih1 = (const float*)d_in[5];
    const float* W_hh1 = (const float*)d_in[6];
    const float* b_ih1 = (const float*)d_in[7];
    const float* b_hh1 = (const float*)d_in[8];
    const float* W_fc  = (const float*)d_in[9];
    const float* b_fc  = (const float*)d_in[10];
    float* out = (float*)d_out;

    const int B = in_sizes[0] / (T_ * IN_);   // 4096
    gesture_rnn_kernel<<<dim3(B / 16), dim3(64), 0, stream>>>(
        x, W_ih0, W_hh0, b_ih0, b_hh0, W_ih1, W_hh1, b_ih1, b_hh1,
        W_fc, b_fc, out);
}